// Round 1
// baseline (1803.389 us; speedup 1.0000x reference)
//
#include <hip/hip_runtime.h>

// EnhancedSpatioTemporalLayer: fused ST-GCN forward.
// B=16, FIN=3, N=170, T=288, H=O=64, K=3, KS=3.
// One block per (b,t): conv -> (per k: Y = cheb_k @ Tmat ; G += Y @ theta_k) -> relu+residual -> out.
// Round 1: fp32 VALU baseline (validates algorithm before MFMA conversion).

#define Bx   16
#define FINx 3
#define Nx   170
#define Tx   288
#define Hx   64
#define Ox   64
#define Kx   3
#define NP   192   // padded row count (multiple of 64)
#define PADW 68    // padded row stride in floats for sTm/sY (272B, 16B-aligned, bank-skewed)
#define MC   34    // cheb chunk rows (170 = 5*34)

__global__ __launch_bounds__(512)
void stgcn_fused_f32(const float* __restrict__ x,
                     const float* __restrict__ cheb,
                     const float* __restrict__ conv_w,
                     const float* __restrict__ conv_b,
                     const float* __restrict__ theta,
                     const float* __restrict__ res_w,
                     const float* __restrict__ res_b,
                     float* __restrict__ out) {
    __shared__ float sTm[NP * PADW];      // conv output [m][c], 52.2 KB
    __shared__ float sY[NP * PADW];       // cheb output [n][c], 52.2 KB
    __shared__ float sCheb[MC * NP];      // cheb chunk [mm][n] (rows as cols via symmetry), 25.5 KB
    __shared__ float sXs[Nx * 9];         // x slice [n][f][j], 6.1 KB
    __shared__ float sTheta[Hx * Ox];     // theta_k, 16 KB
    __shared__ float sResW[Ox * 3];
    __shared__ float sResB[Ox];

    const int tid = threadIdx.x;
    // XCD-chunked swizzle: 4608 blocks = 8 XCDs * 576. Consecutive virtual ids
    // (same b, consecutive t -> shared output cache lines + shared x halo) stay
    // on one XCD's L2.
    const int vid = (blockIdx.x & 7) * 576 + (blockIdx.x >> 3);
    const int b  = vid / Tx;
    const int t0 = vid % Tx;

    // ---- stage x slice (t0-1..t0+1, zero-padded) + small tensors ----
    for (int idx = tid; idx < Nx * 9; idx += 512) {
        int n = idx / 9, r = idx % 9, f = r / 3, j = r % 3;
        int tt = t0 - 1 + j;
        float v = 0.f;
        if (tt >= 0 && tt < Tx) v = x[((b * FINx + f) * Nx + n) * Tx + tt];
        sXs[idx] = v;
    }
    for (int idx = tid; idx < Ox * 3; idx += 512) sResW[idx] = res_w[idx];
    for (int idx = tid; idx < Ox;     idx += 512) sResB[idx] = res_b[idx];

    // per-thread conv weights (c fixed per thread)
    const int cc = tid & 63;
    float wreg[9];
#pragma unroll
    for (int r = 0; r < 9; ++r) wreg[r] = conv_w[cc * 9 + r];
    const float bias = conv_b[cc];

    __syncthreads();

    // ---- temporal conv + ReLU: sTm[m][cc] ----
    for (int m = (tid >> 6); m < Nx; m += 8) {
        float acc = bias;
#pragma unroll
        for (int r = 0; r < 9; ++r) acc += sXs[m * 9 + r] * wreg[r];
        sTm[m * PADW + cc] = fmaxf(acc, 0.f);
    }

    const int tn = tid >> 3;        // 0..63  (rows n = tn + 64*i)
    const int c0 = (tid & 7) * 8;   // 8 consecutive cols per thread

    float G[3][8];
#pragma unroll
    for (int i = 0; i < 3; ++i)
#pragma unroll
        for (int j = 0; j < 8; ++j) G[i][j] = 0.f;

    for (int k = 0; k < Kx; ++k) {
        float Yacc[3][8];
#pragma unroll
        for (int i = 0; i < 3; ++i)
#pragma unroll
            for (int j = 0; j < 8; ++j) Yacc[i][j] = 0.f;

        const float* chebk = cheb + k * Nx * Nx;

        // ---- Y = cheb_k @ Tmat  (cheb_k symmetric: stage rows, use as cols) ----
        for (int m0 = 0; m0 < Nx; m0 += MC) {
            __syncthreads();   // protect sCheb (and, first time, sTm/sY consumers)
            for (int idx = tid; idx < MC * NP; idx += 512) {
                int mm = idx / NP, n = idx % NP;
                sCheb[idx] = (n < Nx) ? chebk[(m0 + mm) * Nx + n] : 0.f;
            }
            __syncthreads();
#pragma unroll 2
            for (int mm = 0; mm < MC; ++mm) {
                float cv0 = sCheb[mm * NP + tn];
                float cv1 = sCheb[mm * NP + tn + 64];
                float cv2 = sCheb[mm * NP + tn + 128];
                const float* tp = &sTm[(m0 + mm) * PADW + c0];
                float tv[8];
#pragma unroll
                for (int j = 0; j < 8; ++j) tv[j] = tp[j];
#pragma unroll
                for (int j = 0; j < 8; ++j) {
                    Yacc[0][j] += cv0 * tv[j];
                    Yacc[1][j] += cv1 * tv[j];
                    Yacc[2][j] += cv2 * tv[j];
                }
            }
        }
        __syncthreads();
#pragma unroll
        for (int i = 0; i < 3; ++i) {
            float* yp = &sY[(tn + 64 * i) * PADW + c0];
#pragma unroll
            for (int j = 0; j < 8; ++j) yp[j] = Yacc[i][j];
        }
        for (int idx = tid; idx < Hx * Ox; idx += 512)
            sTheta[idx] = theta[k * Hx * Ox + idx];
        __syncthreads();

        // ---- G += Y @ theta_k ----
        for (int c = 0; c < Hx; ++c) {
            float y0 = sY[tn * PADW + c];
            float y1 = sY[(tn + 64) * PADW + c];
            float y2 = sY[(tn + 128) * PADW + c];
            const float* thp = &sTheta[c * Ox + c0];
            float th[8];
#pragma unroll
            for (int j = 0; j < 8; ++j) th[j] = thp[j];
#pragma unroll
            for (int j = 0; j < 8; ++j) {
                G[0][j] += y0 * th[j];
                G[1][j] += y1 * th[j];
                G[2][j] += y2 * th[j];
            }
        }
    }

    // ---- epilogue: ReLU(G) + residual, scatter to out[b][o][n][t0] ----
#pragma unroll
    for (int i = 0; i < 3; ++i) {
        int n = tn + 64 * i;
        if (n >= Nx) continue;
        float xf0 = sXs[n * 9 + 1];   // x[b,0,n,t0]
        float xf1 = sXs[n * 9 + 4];   // x[b,1,n,t0]
        float xf2 = sXs[n * 9 + 7];   // x[b,2,n,t0]
#pragma unroll
        for (int j = 0; j < 8; ++j) {
            int o = c0 + j;
            float resv = sResB[o] + xf0 * sResW[o * 3 + 0]
                                  + xf1 * sResW[o * 3 + 1]
                                  + xf2 * sResW[o * 3 + 2];
            float v = fmaxf(G[i][j], 0.f) + resv;
            out[((b * Ox + o) * Nx + n) * Tx + t0] = v;
        }
    }
}

extern "C" void kernel_launch(void* const* d_in, const int* in_sizes, int n_in,
                              void* d_out, int out_size, void* d_ws, size_t ws_size,
                              hipStream_t stream) {
    const float* x      = (const float*)d_in[0];
    // d_in[1] = adj (unused by forward)
    const float* cheb   = (const float*)d_in[2];
    const float* conv_w = (const float*)d_in[3];
    const float* conv_b = (const float*)d_in[4];
    const float* theta  = (const float*)d_in[5];
    const float* res_w  = (const float*)d_in[6];
    const float* res_b  = (const float*)d_in[7];
    float* out = (float*)d_out;

    dim3 grid(Bx * Tx);   // 4608 blocks
    dim3 block(512);
    hipLaunchKernelGGL(stgcn_fused_f32, grid, block, 0, stream,
                       x, cheb, conv_w, conv_b, theta, res_w, res_b, out);
}

// Round 2
// 487.893 us; speedup vs baseline: 3.6963x; 3.6963x over previous
//
#include <hip/hip_runtime.h>
#include <hip/hip_bf16.h>

// EnhancedSpatioTemporalLayer fused forward, bf16-MFMA version.
// B=16, FIN=3, N=170, T=288, H=O=64, K=3, KS=3.
// Per (b,t) block: conv(f32) -> small GEMM Z=Tm@theta (MFMA) -> big GEMM
// GT = ZT @ chebcat (MFMA, cheb symmetric) -> relu + residual -> out.

#define Bx   16
#define FINx 3
#define Nx   170
#define Tx   288
#define Hx   64
#define Ox   64
#define Kx   3
#define NP   192            // padded n/m (12 x 16)
#define KTOT 576            // 3 * 192, big-GEMM K dim
#define TMW  72             // sTm/sTh row stride (bf16): 144B -> 2-way banks
#define ZTW  584            // sZT row stride (bf16): 1168B -> 2-way banks

typedef __attribute__((ext_vector_type(8))) short bf16x8;
typedef __attribute__((ext_vector_type(4))) short bf16x4;
typedef __attribute__((ext_vector_type(4))) float f32x4;

__device__ __align__(16) __hip_bfloat16 g_chebcat[NP * KTOT];  // [n][k*192+m] = cheb_k[n][m]
__device__ __align__(16) __hip_bfloat16 g_thetaT[NP * Hx];     // [k*64+o][c] = theta[k][c][o]

static __device__ __forceinline__ short f2bf(float f) {
    __hip_bfloat16 h = __float2bfloat16(f);
    return *reinterpret_cast<short*>(&h);
}

__global__ __launch_bounds__(512)
void precompute_bf16(const float* __restrict__ cheb, const float* __restrict__ theta) {
    int idx = blockIdx.x * 512 + threadIdx.x;
    if (idx < NP * KTOT) {
        int n = idx / KTOT, kk = idx % KTOT;
        int k = kk / NP, m = kk % NP;
        float v = (n < Nx && m < Nx) ? cheb[(k * Nx + n) * Nx + m] : 0.f;  // symmetric
        g_chebcat[idx] = __float2bfloat16(v);
    } else if (idx < NP * KTOT + NP * Hx) {
        int j = idx - NP * KTOT;
        int c2 = j >> 6, c = j & 63;
        float v = theta[(c2 >> 6) * (Hx * Ox) + c * Ox + (c2 & 63)];
        g_thetaT[j] = __float2bfloat16(v);
    }
}

__global__ __launch_bounds__(512, 2)
void stgcn_mfma(const float* __restrict__ x,
                const float* __restrict__ conv_w,
                const float* __restrict__ conv_b,
                const float* __restrict__ res_w,
                const float* __restrict__ res_b,
                float* __restrict__ out) {
    __shared__ __align__(16) __hip_bfloat16 sTm[NP * TMW];   // conv out [m][c], 27.6 KB
    __shared__ __align__(16) __hip_bfloat16 sTh[NP * TMW];   // thetaT  [c2][c], 27.6 KB
    __shared__ __align__(16) __hip_bfloat16 sZT[Ox * ZTW];   // ZT [o][k*192+m], 74.8 KB
    __shared__ float sXs[Nx * 9];
    __shared__ float sResW[Ox * 3];
    __shared__ float sResB[Ox];

    const int tid = threadIdx.x;
    const int vid = (blockIdx.x & 7) * 576 + (blockIdx.x >> 3);  // XCD-chunked swizzle
    const int b  = vid / Tx;
    const int t0 = vid % Tx;

    // ---- stage x slice, thetaT, residual params ----
    for (int idx = tid; idx < Nx * 9; idx += 512) {
        int n = idx / 9, r = idx % 9, f = r / 3, j = r % 3;
        int tt = t0 - 1 + j;
        float v = 0.f;
        if (tt >= 0 && tt < Tx) v = x[((b * FINx + f) * Nx + n) * Tx + tt];
        sXs[idx] = v;
    }
    for (int ci = tid; ci < NP * 8; ci += 512) {               // thetaT rows: 128B each
        int row = ci >> 3, seg = ci & 7;
        *(int4*)((char*)sTh + row * (TMW * 2) + seg * 16) =
            *(const int4*)((const char*)g_thetaT + row * 128 + seg * 16);
    }
    for (int idx = tid; idx < Ox * 3; idx += 512) sResW[idx] = res_w[idx];
    for (int idx = tid; idx < Ox;     idx += 512) sResB[idx] = res_b[idx];

    const int cc = tid & 63;
    float wreg[9];
#pragma unroll
    for (int r = 0; r < 9; ++r) wreg[r] = conv_w[cc * 9 + r];
    const float bias = conv_b[cc];

    __syncthreads();

    // ---- temporal conv + ReLU -> bf16 sTm[m][cc]; zero pad rows ----
    for (int m = (tid >> 6); m < Nx; m += 8) {
        float acc = bias;
#pragma unroll
        for (int r = 0; r < 9; ++r) acc += sXs[m * 9 + r] * wreg[r];
        sTm[m * TMW + cc] = __float2bfloat16(fmaxf(acc, 0.f));
    }
    for (int idx = tid; idx < (NP - Nx) * 64; idx += 512) {
        int m = Nx + idx / 64, c = idx % 64;
        sTm[m * TMW + c] = __float2bfloat16(0.f);
    }
    __syncthreads();

    const int lane = tid & 63;
    const int w    = tid >> 6;
    const int l16  = lane & 15;
    const int lk   = lane >> 4;   // k-group 0..3

    // ---- small GEMM: OutS[m][c2] = Tm[192x64] @ ThT^T[64x192]; write ZT ----
    {
        const int r2 = w & 3;     // m-tiles  r2*3 + a
        const int cg = w >> 2;    // c2-tiles cg*6 + t
        f32x4 acc[3][6];
#pragma unroll
        for (int a = 0; a < 3; ++a)
#pragma unroll
            for (int t = 0; t < 6; ++t) acc[a][t] = (f32x4)0.f;

#pragma unroll
        for (int s = 0; s < 2; ++s) {
            bf16x8 afr[3], bfr[6];
#pragma unroll
            for (int a = 0; a < 3; ++a) {
                int m = (r2 * 3 + a) * 16 + l16;
                afr[a] = *(const bf16x8*)((const char*)sTm + m * (TMW * 2) + s * 64 + lk * 16);
            }
#pragma unroll
            for (int t = 0; t < 6; ++t) {
                int c2 = (cg * 6 + t) * 16 + l16;
                bfr[t] = *(const bf16x8*)((const char*)sTh + c2 * (TMW * 2) + s * 64 + lk * 16);
            }
#pragma unroll
            for (int a = 0; a < 3; ++a)
#pragma unroll
                for (int t = 0; t < 6; ++t)
                    acc[a][t] = __builtin_amdgcn_mfma_f32_16x16x32_bf16(afr[a], bfr[t], acc[a][t], 0, 0, 0);
        }
#pragma unroll
        for (int a = 0; a < 3; ++a)
#pragma unroll
            for (int t = 0; t < 6; ++t) {
                int c2 = (cg * 6 + t) * 16 + l16;
                int o = c2 & 63, k = c2 >> 6;
                int m0 = (r2 * 3 + a) * 16 + lk * 4;
                bf16x4 v;
#pragma unroll
                for (int r = 0; r < 4; ++r) v[r] = f2bf(acc[a][t][r]);
                *(bf16x4*)((char*)sZT + o * (ZTW * 2) + (k * NP + m0) * 2) = v;
            }
    }
    __syncthreads();

    // ---- big GEMM: GT[64x192] = ZT[64x576] @ chebcat^T-frags (global/L2) ----
    const int wr = w & 1;         // o-tiles  wr*2 + oi
    const int wc = w >> 1;        // n-tiles  wc*3 + nj
    f32x4 acc[2][3];
#pragma unroll
    for (int oi = 0; oi < 2; ++oi)
#pragma unroll
        for (int nj = 0; nj < 3; ++nj) acc[oi][nj] = (f32x4)0.f;

    const char* chebbase = (const char*)g_chebcat;
#pragma unroll
    for (int s = 0; s < 18; ++s) {
        bf16x8 afr[2], bfr[3];
#pragma unroll
        for (int oi = 0; oi < 2; ++oi) {
            int o = wr * 32 + oi * 16 + l16;
            afr[oi] = *(const bf16x8*)((const char*)sZT + o * (ZTW * 2) + s * 64 + lk * 16);
        }
#pragma unroll
        for (int nj = 0; nj < 3; ++nj) {
            int n = (wc * 3 + nj) * 16 + l16;
            bfr[nj] = *(const bf16x8*)(chebbase + n * (KTOT * 2) + s * 64 + lk * 16);
        }
#pragma unroll
        for (int oi = 0; oi < 2; ++oi)
#pragma unroll
            for (int nj = 0; nj < 3; ++nj)
                acc[oi][nj] = __builtin_amdgcn_mfma_f32_16x16x32_bf16(afr[oi], bfr[nj], acc[oi][nj], 0, 0, 0);
    }

    // ---- epilogue: relu + residual, scatter store ----
#pragma unroll
    for (int nj = 0; nj < 3; ++nj) {
        int n = (wc * 3 + nj) * 16 + l16;
        if (n < Nx) {
            float xf0 = sXs[n * 9 + 1];
            float xf1 = sXs[n * 9 + 4];
            float xf2 = sXs[n * 9 + 7];
#pragma unroll
            for (int oi = 0; oi < 2; ++oi) {
#pragma unroll
                for (int r = 0; r < 4; ++r) {
                    int o = wr * 32 + oi * 16 + lk * 4 + r;
                    float resv = sResB[o] + xf0 * sResW[o * 3 + 0]
                                          + xf1 * sResW[o * 3 + 1]
                                          + xf2 * sResW[o * 3 + 2];
                    out[((b * Ox + o) * Nx + n) * Tx + t0] =
                        fmaxf(acc[oi][nj][r], 0.f) + resv;
                }
            }
        }
    }
}

extern "C" void kernel_launch(void* const* d_in, const int* in_sizes, int n_in,
                              void* d_out, int out_size, void* d_ws, size_t ws_size,
                              hipStream_t stream) {
    const float* x      = (const float*)d_in[0];
    const float* cheb   = (const float*)d_in[2];
    const float* conv_w = (const float*)d_in[3];
    const float* conv_b = (const float*)d_in[4];
    const float* theta  = (const float*)d_in[5];
    const float* res_w  = (const float*)d_in[6];
    const float* res_b  = (const float*)d_in[7];
    float* out = (float*)d_out;

    int pre_elems = NP * KTOT + NP * Hx;
    hipLaunchKernelGGL(precompute_bf16, dim3((pre_elems + 511) / 512), dim3(512), 0, stream,
                       cheb, theta);
    hipLaunchKernelGGL(stgcn_mfma, dim3(Bx * Tx), dim3(512), 0, stream,
                       x, conv_w, conv_b, res_w, res_b, out);
}